// Round 9
// baseline (714.849 us; speedup 1.0000x reference)
//
#include <hip/hip_runtime.h>
#include <math.h>

#define BS 8
#define SEQ 1024
#define DIM 1024
#define FF 4096
#define NE 8
#define NSLOT 16
#define MAXM 8
#define NCHUNK 64

#define KS_UG 4
#define KC_UG (DIM / KS_UG)   // 256 floats per k-chunk
#define KS_DN 16
#define KC_DN (FF / KS_DN)    // 256 floats per k-chunk

// ws float offsets
#define WS_LPART 0                               // 4096
#define WS_SELW  (WS_LPART + BS*NCHUNK*NE)       // 16
#define WS_SELE  (WS_SELW + NSLOT)               // 16 (ints)
#define WS_ACT   (WS_SELE + NSLOT)               // [NSLOT][FF] = 65536
#define WS_UPP   (WS_ACT + NSLOT*FF)             // [KS_UG][NSLOT][FF] = 262144
#define WS_GTP   (WS_UPP + KS_UG*NSLOT*FF)       // 262144
#define WS_YP    WS_UPP                          // alias (upp dead after kact)
#define WS_Y     (WS_GTP + KS_UG*NSLOT*FF)       // 16384

__device__ __forceinline__ float dot4(float4 a, float4 b) {
    return a.x*b.x + a.y*b.y + a.z*b.z + a.w*b.w;
}

// ---- 1. h-chunk sum fused with router dot ----
__global__ __launch_bounds__(256) void klogit(const float4* __restrict__ h4,
                                              const float4* __restrict__ rw4,
                                              float* __restrict__ lpart) {
    const int c = blockIdx.x, b = blockIdx.y, t = threadIdx.x;
    const float4* p = h4 + ((size_t)b * SEQ + (size_t)c * 16) * (DIM/4) + t;
    float4 s = make_float4(0.f, 0.f, 0.f, 0.f);
    #pragma unroll
    for (int i = 0; i < 16; ++i) {
        float4 v = p[(size_t)i * (DIM/4)];
        s.x += v.x; s.y += v.y; s.z += v.z; s.w += v.w;
    }
    float pd[NE];
    #pragma unroll
    for (int e = 0; e < NE; ++e) pd[e] = dot4(s, rw4[(size_t)e * (DIM/4) + t]);
    #pragma unroll
    for (int o = 32; o; o >>= 1) {
        #pragma unroll
        for (int e = 0; e < NE; ++e) pd[e] += __shfl_xor(pd[e], o);
    }
    __shared__ float red[4][NE];
    const int wave = t >> 6, lane = t & 63;
    if (lane == 0) {
        #pragma unroll
        for (int e = 0; e < NE; ++e) red[wave][e] = pd[e];
    }
    __syncthreads();
    if (t < NE)
        lpart[(size_t)(b * NCHUNK + c) * NE + t] =
            red[0][t] + red[1][t] + red[2][t] + red[3][t];
}

// ---- 2. final logits + softmax + top2 ----
__global__ void krouter2(const float* __restrict__ lpart,
                         float* __restrict__ out_logits,
                         float* __restrict__ selw, int* __restrict__ sele) {
    const int t = threadIdx.x;  // 64
    __shared__ float lg[BS * NE];
    if (t < BS * NE) {
        const int b = t >> 3, e = t & 7;
        float s = 0.f;
        for (int c = 0; c < NCHUNK; ++c) s += lpart[(size_t)(b * NCHUNK + c) * NE + e];
        s *= (1.0f / (float)SEQ);
        lg[b * NE + e] = s;
        out_logits[b * NE + e] = s;
    }
    __syncthreads();
    if (t < BS) {
        float l[NE]; float mx = -1e30f;
        #pragma unroll
        for (int e = 0; e < NE; ++e) { l[e] = lg[t * NE + e]; mx = fmaxf(mx, l[e]); }
        float sum = 0.f;
        #pragma unroll
        for (int e = 0; e < NE; ++e) { l[e] = expf(l[e] - mx); sum += l[e]; }
        const float invs = 1.f / sum;
        float v1 = -1.f, v2 = -1.f; int e1 = -1, e2 = -1;
        #pragma unroll
        for (int e = 0; e < NE; ++e) {
            float pe = l[e] * invs;
            if (pe > v1)      { v2 = v1; e2 = e1; v1 = pe; e1 = e; }
            else if (pe > v2) { v2 = pe; e2 = e; }
        }
        selw[t * 2 + 0] = v1; sele[t * 2 + 0] = e1;
        selw[t * 2 + 1] = v2; sele[t * 2 + 1] = e2;
    }
}

__device__ __forceinline__ int build_slots(const int* __restrict__ sele, int e, int* slot) {
    unsigned mask = 0;
    #pragma unroll
    for (int s = 0; s < NSLOT; ++s) mask |= (sele[s] == e) ? (1u << s) : 0u;
    const int m = __popc(mask);
    unsigned mm = mask;
    #pragma unroll
    for (int ti = 0; ti < MAXM; ++ti) { slot[ti] = __ffs(mm) - 1; mm &= mm - 1; }
    return m;
}

__device__ __forceinline__ void slots_to_lds(const int* __restrict__ sele, int e,
                                             int t, int* sslot) {
    if (t < MAXM) {
        unsigned mask = 0;
        #pragma unroll
        for (int s = 0; s < NSLOT; ++s) mask |= (sele[s] == e) ? (1u << s) : 0u;
        unsigned mm = mask; int sl = -1;
        for (int k = 0; k <= t; ++k) { sl = __ffs(mm) - 1; mm &= mm - 1; }
        sslot[t] = sl;
    }
}

// ======== GEMV core: lane-owns-row, 128B full-line bursts, ping-pong ========
// KC = 256 floats per k-chunk -> 8 bursts of 8 float4 (128B) per lane.
#define GLD(Wr, C) {                                   \
    _Pragma("unroll")                                  \
    for (int i_ = 0; i_ < 8; ++i_) Wr[i_] = wp[(C) * 8 + i_]; }

#define GFMA(Wr, C) {                                                   \
    _Pragma("unroll")                                                   \
    for (int i_ = 0; i_ < 8; ++i_) {                                    \
        _Pragma("unroll")                                               \
        for (int ti_ = 0; ti_ < MAXM; ++ti_)                            \
            acc[ti_] += dot4(Wr[i_], xs4[ti_ * 64 + (C) * 8 + i_]);     \
    } }

__device__ __forceinline__ void gemv8(const float4* __restrict__ wp,
                                      const float4* __restrict__ xs4,
                                      float* __restrict__ outp, int ostride,
                                      const int* slot, int m, int row) {
    float acc[MAXM];
    #pragma unroll
    for (int ti = 0; ti < MAXM; ++ti) acc[ti] = 0.f;
    float4 W0[8], W1[8];
    GLD(W0, 0)
    GLD(W1, 1)
    GFMA(W0, 0)
    GLD(W0, 2)
    GFMA(W1, 1)
    GLD(W1, 3)
    GFMA(W0, 2)
    GLD(W0, 4)
    GFMA(W1, 3)
    GLD(W1, 5)
    GFMA(W0, 4)
    GLD(W0, 6)
    GFMA(W1, 5)
    GLD(W1, 7)
    GFMA(W0, 6)
    GFMA(W1, 7)
    #pragma unroll
    for (int ti = 0; ti < MAXM; ++ti)
        if (ti < m) outp[(size_t)slot[ti] * ostride + row] = acc[ti];
}

// ---- 3. up/gate partials: grid z = (mat, ks) ----
__global__ __launch_bounds__(256) void kswiglu(const float* __restrict__ h,
                                               const float* __restrict__ w1,
                                               const float* __restrict__ w3,
                                               const int* __restrict__ sele,
                                               float* __restrict__ upp,
                                               float* __restrict__ gtp) {
    __shared__ float xs[MAXM * KC_UG];   // 8 KB
    __shared__ int sslot[MAXM];
    const int tile = blockIdx.x, e = blockIdx.y, t = threadIdx.x;
    const int mat = blockIdx.z & 1, ks = blockIdx.z >> 1;
    int slot[MAXM];
    const int m = build_slots(sele, e, slot);
    if (m == 0) return;
    slots_to_lds(sele, e, t, sslot);
    __syncthreads();
    {   // stage x chunks (zero-fill unused)
        float4* xs4 = (float4*)xs;
        const float4* h4 = (const float4*)h;
        #pragma unroll
        for (int q = 0; q < 2; ++q) {
            const int idx = t + q * 256;
            const int ti = idx >> 6, j = idx & 63;
            const int s = sslot[ti];
            float4 v = make_float4(0.f, 0.f, 0.f, 0.f);
            if (ti < m)
                v = h4[((size_t)((s >> 1) * SEQ + (s & 1))) * (DIM/4) + ks * (KC_UG/4) + j];
            xs4[idx] = v;
        }
    }
    __syncthreads();
    const int wave = t >> 6, lane = t & 63;
    const int row = tile * 256 + wave * 64 + lane;
    const float* wmat = mat ? w3 : w1;
    const float4* wp = (const float4*)wmat + ((size_t)e * FF + row) * (DIM/4) + ks * (KC_UG/4);
    float* outp = (mat ? gtp : upp) + (size_t)ks * NSLOT * FF;
    gemv8(wp, (const float4*)xs, outp, FF, slot, m, row);
}

// ---- 4. combine up/gate partials + silu -> act ----
__global__ __launch_bounds__(256) void kact(const float* __restrict__ upp,
                                            const float* __restrict__ gtp,
                                            float* __restrict__ act) {
    const int r = blockIdx.x * 256 + threadIdx.x, s = blockIdx.y;
    float u = 0.f, g = 0.f;
    #pragma unroll
    for (int ks = 0; ks < KS_UG; ++ks) {
        u += upp[((size_t)ks * NSLOT + s) * FF + r];
        g += gtp[((size_t)ks * NSLOT + s) * FF + r];
    }
    act[(size_t)s * FF + r] = (u / (1.f + expf(-u))) * g;
}

// ---- 5. down partials ----
__global__ __launch_bounds__(256) void kdown(const float* __restrict__ w2,
                                             const float* __restrict__ act,
                                             const int* __restrict__ sele,
                                             float* __restrict__ yp) {
    __shared__ float xs[MAXM * KC_DN];   // 8 KB
    __shared__ int sslot[MAXM];
    const int tile = blockIdx.x, e = blockIdx.y, ks = blockIdx.z, t = threadIdx.x;
    int slot[MAXM];
    const int m = build_slots(sele, e, slot);
    if (m == 0) return;
    slots_to_lds(sele, e, t, sslot);
    __syncthreads();
    {   // stage act chunks
        float4* xs4 = (float4*)xs;
        const float4* a4 = (const float4*)act;
        #pragma unroll
        for (int q = 0; q < 2; ++q) {
            const int idx = t + q * 256;
            const int ti = idx >> 6, j = idx & 63;
            const int s = sslot[ti];
            float4 v = make_float4(0.f, 0.f, 0.f, 0.f);
            if (ti < m) v = a4[(size_t)s * (FF/4) + ks * (KC_DN/4) + j];
            xs4[idx] = v;
        }
    }
    __syncthreads();
    const int wave = t >> 6, lane = t & 63;
    const int row = tile * 256 + wave * 64 + lane;
    const float4* wp = (const float4*)w2 + ((size_t)e * DIM + row) * (FF/4) + ks * (KC_DN/4);
    float* y_out = yp + (size_t)ks * NSLOT * DIM;
    gemv8(wp, (const float4*)xs, y_out, DIM, slot, m, row);
}

// ---- 6. combine down partials x selw -> y ----
__global__ __launch_bounds__(256) void kcomby(const float* __restrict__ yp,
                                              const float* __restrict__ selw,
                                              float* __restrict__ y) {
    const int r = blockIdx.x * 256 + threadIdx.x, s = blockIdx.y;
    float v = 0.f;
    #pragma unroll
    for (int ks = 0; ks < KS_DN; ++ks)
        v += yp[((size_t)ks * NSLOT + s) * DIM + r];
    y[(size_t)s * DIM + r] = selw[s] * v;
}

// ---- 7. combine two selections per batch, broadcast across L ----
__global__ __launch_bounds__(256) void kbcast(const float4* __restrict__ y4,
                                              float4* __restrict__ out4) {
    const int b = blockIdx.y, lg = blockIdx.x, t = threadIdx.x;
    float4 y0 = y4[(size_t)(2 * b) * (DIM/4) + t];
    float4 y1 = y4[(size_t)(2 * b + 1) * (DIM/4) + t];
    float4 c = make_float4(y0.x + y1.x, y0.y + y1.y, y0.z + y1.z, y0.w + y1.w);
    size_t base = ((size_t)b * SEQ + (size_t)lg * 8) * (DIM/4) + t;
    #pragma unroll
    for (int i = 0; i < 8; ++i) out4[base + (size_t)i * (DIM/4)] = c;
}

extern "C" void kernel_launch(void* const* d_in, const int* in_sizes, int n_in,
                              void* d_out, int out_size, void* d_ws, size_t ws_size,
                              hipStream_t stream) {
    const float* h  = (const float*)d_in[0];
    const float* rw = (const float*)d_in[1];
    const float* w1 = (const float*)d_in[2];
    const float* w2 = (const float*)d_in[3];
    const float* w3 = (const float*)d_in[4];
    float* out = (float*)d_out;
    float* ws  = (float*)d_ws;

    float* lpart = ws + WS_LPART;
    float* selw  = ws + WS_SELW;
    int*   sele  = (int*)(ws + WS_SELE);
    float* act   = ws + WS_ACT;
    float* upp   = ws + WS_UPP;
    float* gtp   = ws + WS_GTP;
    float* yp    = ws + WS_YP;
    float* y     = ws + WS_Y;
    float* out_logits = out + (size_t)BS * SEQ * DIM;

    klogit  <<<dim3(NCHUNK, BS), 256, 0, stream>>>((const float4*)h, (const float4*)rw, lpart);
    krouter2<<<1, 64, 0, stream>>>(lpart, out_logits, selw, sele);
    kswiglu <<<dim3(FF / 256, NE, 2 * KS_UG), 256, 0, stream>>>(h, w1, w3, sele, upp, gtp);
    kact    <<<dim3(FF / 256, NSLOT), 256, 0, stream>>>(upp, gtp, act);
    kdown   <<<dim3(DIM / 256, NE, KS_DN), 256, 0, stream>>>(w2, act, sele, yp);
    kcomby  <<<dim3(DIM / 256, NSLOT), 256, 0, stream>>>(yp, selw, y);
    kbcast  <<<dim3(SEQ / 8, BS), 256, 0, stream>>>((const float4*)y, (float4*)out);
}

// Round 10
// 430.225 us; speedup vs baseline: 1.6616x; 1.6616x over previous
//
#include <hip/hip_runtime.h>
#include <math.h>

#define BS 8
#define SEQ 1024
#define DIM 1024
#define FF 4096
#define NE 8
#define NSLOT 16
#define MAXM 8
#define NCHUNK 64

#define KS_UG 4
#define KC_UG (DIM / KS_UG)   // 256 floats per k-chunk
#define KS_DN 16
#define KC_DN (FF / KS_DN)    // 256 floats per k-chunk

// ws float offsets
#define WS_LPART 0                               // 4096
#define WS_SELW  (WS_LPART + BS*NCHUNK*NE)       // 16
#define WS_SELE  (WS_SELW + NSLOT)               // 16 (ints)
#define WS_ACT   (WS_SELE + NSLOT)               // [NSLOT][FF] = 65536
#define WS_UPP   (WS_ACT + NSLOT*FF)             // [KS_UG][NSLOT][FF] = 262144
#define WS_GTP   (WS_UPP + KS_UG*NSLOT*FF)       // 262144
#define WS_YP    WS_UPP                          // alias (upp dead after kact)
#define WS_Y     (WS_GTP + KS_UG*NSLOT*FF)       // 16384

__device__ __forceinline__ float dot4(float4 a, float4 b) {
    return a.x*b.x + a.y*b.y + a.z*b.z + a.w*b.w;
}

// ---- 1. h-chunk sum fused with router dot ----
__global__ __launch_bounds__(256) void klogit(const float4* __restrict__ h4,
                                              const float4* __restrict__ rw4,
                                              float* __restrict__ lpart) {
    const int c = blockIdx.x, b = blockIdx.y, t = threadIdx.x;
    const float4* p = h4 + ((size_t)b * SEQ + (size_t)c * 16) * (DIM/4) + t;
    float4 s = make_float4(0.f, 0.f, 0.f, 0.f);
    #pragma unroll
    for (int i = 0; i < 16; ++i) {
        float4 v = p[(size_t)i * (DIM/4)];
        s.x += v.x; s.y += v.y; s.z += v.z; s.w += v.w;
    }
    float pd[NE];
    #pragma unroll
    for (int e = 0; e < NE; ++e) pd[e] = dot4(s, rw4[(size_t)e * (DIM/4) + t]);
    #pragma unroll
    for (int o = 32; o; o >>= 1) {
        #pragma unroll
        for (int e = 0; e < NE; ++e) pd[e] += __shfl_xor(pd[e], o);
    }
    __shared__ float red[4][NE];
    const int wave = t >> 6, lane = t & 63;
    if (lane == 0) {
        #pragma unroll
        for (int e = 0; e < NE; ++e) red[wave][e] = pd[e];
    }
    __syncthreads();
    if (t < NE)
        lpart[(size_t)(b * NCHUNK + c) * NE + t] =
            red[0][t] + red[1][t] + red[2][t] + red[3][t];
}

// ---- 2. final logits + softmax + top2 ----
__global__ void krouter2(const float* __restrict__ lpart,
                         float* __restrict__ out_logits,
                         float* __restrict__ selw, int* __restrict__ sele) {
    const int t = threadIdx.x;  // 64
    __shared__ float lg[BS * NE];
    if (t < BS * NE) {
        const int b = t >> 3, e = t & 7;
        float s = 0.f;
        for (int c = 0; c < NCHUNK; ++c) s += lpart[(size_t)(b * NCHUNK + c) * NE + e];
        s *= (1.0f / (float)SEQ);
        lg[b * NE + e] = s;
        out_logits[b * NE + e] = s;
    }
    __syncthreads();
    if (t < BS) {
        float l[NE]; float mx = -1e30f;
        #pragma unroll
        for (int e = 0; e < NE; ++e) { l[e] = lg[t * NE + e]; mx = fmaxf(mx, l[e]); }
        float sum = 0.f;
        #pragma unroll
        for (int e = 0; e < NE; ++e) { l[e] = expf(l[e] - mx); sum += l[e]; }
        const float invs = 1.f / sum;
        float v1 = -1.f, v2 = -1.f; int e1 = -1, e2 = -1;
        #pragma unroll
        for (int e = 0; e < NE; ++e) {
            float pe = l[e] * invs;
            if (pe > v1)      { v2 = v1; e2 = e1; v1 = pe; e1 = e; }
            else if (pe > v2) { v2 = pe; e2 = e; }
        }
        selw[t * 2 + 0] = v1; sele[t * 2 + 0] = e1;
        selw[t * 2 + 1] = v2; sele[t * 2 + 1] = e2;
    }
}

__device__ __forceinline__ int build_slots(const int* __restrict__ sele, int e, int* slot) {
    unsigned mask = 0;
    #pragma unroll
    for (int s = 0; s < NSLOT; ++s) mask |= (sele[s] == e) ? (1u << s) : 0u;
    const int m = __popc(mask);
    unsigned mm = mask;
    #pragma unroll
    for (int ti = 0; ti < MAXM; ++ti) { slot[ti] = __ffs(mm) - 1; mm &= mm - 1; }
    return m;
}

__device__ __forceinline__ void slots_to_lds(const int* __restrict__ sele, int e,
                                             int t, int* sslot) {
    if (t < MAXM) {
        unsigned mask = 0;
        #pragma unroll
        for (int s = 0; s < NSLOT; ++s) mask |= (sele[s] == e) ? (1u << s) : 0u;
        unsigned mm = mask; int sl = -1;
        for (int k = 0; k <= t; ++k) { sl = __ffs(mm) - 1; mm &= mm - 1; }
        sslot[t] = sl;
    }
}

// ======== paired-lane GEMV pieces ========
// lane pair owns rows (r0, r0+32); lane reads its 64B half-line of each.
// KC=256 floats -> 8 line-iters; runtime loop (#pragma unroll 1) stops hoisting.
#define PL_LOAD(Adst, Bdst, LL) {                      \
    _Pragma("unroll")                                  \
    for (int i_ = 0; i_ < 4; ++i_) {                   \
        Adst[i_] = wp0[(LL) * 8 + i_];                 \
        Bdst[i_] = wp1[(LL) * 8 + i_];                 \
    } }

#define PL_FMA(Asrc, Bsrc, LL) {                                  \
    _Pragma("unroll")                                             \
    for (int i_ = 0; i_ < 4; ++i_) {                              \
        _Pragma("unroll")                                         \
        for (int ti_ = 0; ti_ < MAXM; ++ti_) {                    \
            float4 x_ = xs4[ti_ * 64 + (LL) * 8 + i_];            \
            acc0[ti_] += dot4(Asrc[i_], x_);                      \
            acc1[ti_] += dot4(Bsrc[i_], x_);                      \
        }                                                         \
    } }

#define PL_GEMV_LOOP() {                        \
    PL_LOAD(A0, B0, 0)                          \
    _Pragma("unroll 1")                         \
    for (int L = 0; L < 6; L += 2) {            \
        PL_LOAD(A1, B1, L + 1)                  \
        PL_FMA(A0, B0, L)                       \
        PL_LOAD(A0, B0, L + 2)                  \
        PL_FMA(A1, B1, L + 1)                   \
    }                                           \
    PL_LOAD(A1, B1, 7)                          \
    PL_FMA(A0, B0, 6)                           \
    PL_FMA(A1, B1, 7)                           \
    }

// ---- 3. up/gate partials: grid z = (mat, ks) ----
__global__ __launch_bounds__(256, 4) void kswiglu(const float* __restrict__ h,
                                                  const float* __restrict__ w1,
                                                  const float* __restrict__ w3,
                                                  const int* __restrict__ sele,
                                                  float* __restrict__ upp,
                                                  float* __restrict__ gtp) {
    __shared__ float xs[MAXM * KC_UG];   // 8 KB
    __shared__ int sslot[MAXM];
    const int tile = blockIdx.x, e = blockIdx.y, t = threadIdx.x;
    const int mat = blockIdx.z & 1, ks = blockIdx.z >> 1;
    int slot[MAXM];
    const int m = build_slots(sele, e, slot);
    if (m == 0) return;
    slots_to_lds(sele, e, t, sslot);
    __syncthreads();
    {   // stage x chunks (zero-fill unused): 512 f4, 2 per thread
        float4* xsw = (float4*)xs;
        const float4* h4 = (const float4*)h;
        #pragma unroll
        for (int q = 0; q < 2; ++q) {
            const int idx = t + q * 256;
            const int ti = idx >> 6, j = idx & 63;
            const int s = sslot[ti];
            float4 v = make_float4(0.f, 0.f, 0.f, 0.f);
            if (ti < m)
                v = h4[((size_t)((s >> 1) * SEQ + (s & 1))) * (DIM/4) + ks * (KC_UG/4) + j];
            xsw[idx] = v;
        }
    }
    __syncthreads();
    const int wave = t >> 6, lane = t & 63;
    const int p = lane >> 1, hh = lane & 1;
    const int r0 = tile * 256 + wave * 64 + p;           // second row = r0 + 32
    const float4* wbase = (const float4*)(mat ? w3 : w1) + (size_t)e * FF * (DIM/4);
    const float4* wp0 = wbase + (size_t)r0 * (DIM/4) + ks * (KC_UG/4) + hh * 4;
    const float4* wp1 = wbase + (size_t)(r0 + 32) * (DIM/4) + ks * (KC_UG/4) + hh * 4;
    const float4* xs4 = (const float4*)xs + hh * 4;
    float acc0[MAXM], acc1[MAXM];
    #pragma unroll
    for (int ti = 0; ti < MAXM; ++ti) { acc0[ti] = 0.f; acc1[ti] = 0.f; }
    float4 A0[4], B0[4], A1[4], B1[4];
    PL_GEMV_LOOP()
    float* outp = (mat ? gtp : upp) + (size_t)ks * NSLOT * FF;
    #pragma unroll
    for (int ti = 0; ti < MAXM; ++ti) {
        float v0 = acc0[ti] + __shfl_xor(acc0[ti], 1);
        float v1 = acc1[ti] + __shfl_xor(acc1[ti], 1);
        if (ti < m) {
            if (hh == 0) outp[(size_t)slot[ti] * FF + r0] = v0;
            else         outp[(size_t)slot[ti] * FF + r0 + 32] = v1;
        }
    }
}

// ---- 4. combine up/gate partials + silu -> act ----
__global__ __launch_bounds__(256) void kact(const float* __restrict__ upp,
                                            const float* __restrict__ gtp,
                                            float* __restrict__ act) {
    const int r = blockIdx.x * 256 + threadIdx.x, s = blockIdx.y;
    float u = 0.f, g = 0.f;
    #pragma unroll
    for (int ks = 0; ks < KS_UG; ++ks) {
        u += upp[((size_t)ks * NSLOT + s) * FF + r];
        g += gtp[((size_t)ks * NSLOT + s) * FF + r];
    }
    act[(size_t)s * FF + r] = (u / (1.f + expf(-u))) * g;
}

// ---- 5. down partials ----
__global__ __launch_bounds__(256, 4) void kdown(const float* __restrict__ w2,
                                                const float* __restrict__ act,
                                                const int* __restrict__ sele,
                                                float* __restrict__ yp) {
    __shared__ float xs[MAXM * KC_DN];   // 8 KB
    __shared__ int sslot[MAXM];
    const int tile = blockIdx.x, e = blockIdx.y, ks = blockIdx.z, t = threadIdx.x;
    int slot[MAXM];
    const int m = build_slots(sele, e, slot);
    if (m == 0) return;
    slots_to_lds(sele, e, t, sslot);
    __syncthreads();
    {   // stage act chunks
        float4* xsw = (float4*)xs;
        const float4* a4 = (const float4*)act;
        #pragma unroll
        for (int q = 0; q < 2; ++q) {
            const int idx = t + q * 256;
            const int ti = idx >> 6, j = idx & 63;
            const int s = sslot[ti];
            float4 v = make_float4(0.f, 0.f, 0.f, 0.f);
            if (ti < m) v = a4[(size_t)s * (FF/4) + ks * (KC_DN/4) + j];
            xsw[idx] = v;
        }
    }
    __syncthreads();
    const int wave = t >> 6, lane = t & 63;
    const int p = lane >> 1, hh = lane & 1;
    const int r0 = tile * 256 + wave * 64 + p;           // second row = r0 + 32
    const float4* wbase = (const float4*)w2 + (size_t)e * DIM * (FF/4);
    const float4* wp0 = wbase + (size_t)r0 * (FF/4) + ks * (KC_DN/4) + hh * 4;
    const float4* wp1 = wbase + (size_t)(r0 + 32) * (FF/4) + ks * (KC_DN/4) + hh * 4;
    const float4* xs4 = (const float4*)xs + hh * 4;
    float acc0[MAXM], acc1[MAXM];
    #pragma unroll
    for (int ti = 0; ti < MAXM; ++ti) { acc0[ti] = 0.f; acc1[ti] = 0.f; }
    float4 A0[4], B0[4], A1[4], B1[4];
    PL_GEMV_LOOP()
    float* outp = yp + (size_t)ks * NSLOT * DIM;
    #pragma unroll
    for (int ti = 0; ti < MAXM; ++ti) {
        float v0 = acc0[ti] + __shfl_xor(acc0[ti], 1);
        float v1 = acc1[ti] + __shfl_xor(acc1[ti], 1);
        if (ti < m) {
            if (hh == 0) outp[(size_t)slot[ti] * DIM + r0] = v0;
            else         outp[(size_t)slot[ti] * DIM + r0 + 32] = v1;
        }
    }
}

// ---- 6. combine down partials x selw -> y ----
__global__ __launch_bounds__(256) void kcomby(const float* __restrict__ yp,
                                              const float* __restrict__ selw,
                                              float* __restrict__ y) {
    const int r = blockIdx.x * 256 + threadIdx.x, s = blockIdx.y;
    float v = 0.f;
    #pragma unroll
    for (int ks = 0; ks < KS_DN; ++ks)
        v += yp[((size_t)ks * NSLOT + s) * DIM + r];
    y[(size_t)s * DIM + r] = selw[s] * v;
}

// ---- 7. combine two selections per batch, broadcast across L ----
__global__ __launch_bounds__(256) void kbcast(const float4* __restrict__ y4,
                                              float4* __restrict__ out4) {
    const int b = blockIdx.y, lg = blockIdx.x, t = threadIdx.x;
    float4 y0 = y4[(size_t)(2 * b) * (DIM/4) + t];
    float4 y1 = y4[(size_t)(2 * b + 1) * (DIM/4) + t];
    float4 c = make_float4(y0.x + y1.x, y0.y + y1.y, y0.z + y1.z, y0.w + y1.w);
    size_t base = ((size_t)b * SEQ + (size_t)lg * 8) * (DIM/4) + t;
    #pragma unroll
    for (int i = 0; i < 8; ++i) out4[base + (size_t)i * (DIM/4)] = c;
}

extern "C" void kernel_launch(void* const* d_in, const int* in_sizes, int n_in,
                              void* d_out, int out_size, void* d_ws, size_t ws_size,
                              hipStream_t stream) {
    const float* h  = (const float*)d_in[0];
    const float* rw = (const float*)d_in[1];
    const float* w1 = (const float*)d_in[2];
    const float* w2 = (const float*)d_in[3];
    const float* w3 = (const float*)d_in[4];
    float* out = (float*)d_out;
    float* ws  = (float*)d_ws;

    float* lpart = ws + WS_LPART;
    float* selw  = ws + WS_SELW;
    int*   sele  = (int*)(ws + WS_SELE);
    float* act   = ws + WS_ACT;
    float* upp   = ws + WS_UPP;
    float* gtp   = ws + WS_GTP;
    float* yp    = ws + WS_YP;
    float* y     = ws + WS_Y;
    float* out_logits = out + (size_t)BS * SEQ * DIM;

    klogit  <<<dim3(NCHUNK, BS), 256, 0, stream>>>((const float4*)h, (const float4*)rw, lpart);
    krouter2<<<1, 64, 0, stream>>>(lpart, out_logits, selw, sele);
    kswiglu <<<dim3(FF / 256, NE, 2 * KS_UG), 256, 0, stream>>>(h, w1, w3, sele, upp, gtp);
    kact    <<<dim3(FF / 256, NSLOT), 256, 0, stream>>>(upp, gtp, act);
    kdown   <<<dim3(DIM / 256, NE, KS_DN), 256, 0, stream>>>(w2, act, sele, yp);
    kcomby  <<<dim3(DIM / 256, NSLOT), 256, 0, stream>>>(yp, selw, y);
    kbcast  <<<dim3(SEQ / 8, BS), 256, 0, stream>>>((const float4*)y, (float4*)out);
}

// Round 11
// 213.857 us; speedup vs baseline: 3.3427x; 2.0117x over previous
//
#include <hip/hip_runtime.h>
#include <math.h>

#define BS 8
#define SEQ 1024
#define DIM 1024
#define FF 4096
#define NE 8
#define NSLOT 16
#define MAXM 8
#define NCHUNK 64

// ws float offsets
#define WS_LPART 0
#define WS_SELW  (WS_LPART + BS*NCHUNK*NE)
#define WS_SELE  (WS_SELW + NSLOT)
#define WS_ACT   (WS_SELE + NSLOT)          // [NSLOT][FF]
#define WS_Y     (WS_ACT + NSLOT*FF)        // [NSLOT][DIM]

__device__ __forceinline__ float dot4(float4 a, float4 b) {
    return a.x*b.x + a.y*b.y + a.z*b.z + a.w*b.w;
}

// ---- 1. h-chunk sum fused with router dot ----
__global__ __launch_bounds__(256) void klogit(const float4* __restrict__ h4,
                                              const float4* __restrict__ rw4,
                                              float* __restrict__ lpart) {
    const int c = blockIdx.x, b = blockIdx.y, t = threadIdx.x;
    const float4* p = h4 + ((size_t)b * SEQ + (size_t)c * 16) * (DIM/4) + t;
    float4 s = make_float4(0.f, 0.f, 0.f, 0.f);
    #pragma unroll
    for (int i = 0; i < 16; ++i) {
        float4 v = p[(size_t)i * (DIM/4)];
        s.x += v.x; s.y += v.y; s.z += v.z; s.w += v.w;
    }
    float pd[NE];
    #pragma unroll
    for (int e = 0; e < NE; ++e) pd[e] = dot4(s, rw4[(size_t)e * (DIM/4) + t]);
    #pragma unroll
    for (int o = 32; o; o >>= 1) {
        #pragma unroll
        for (int e = 0; e < NE; ++e) pd[e] += __shfl_xor(pd[e], o);
    }
    __shared__ float red[4][NE];
    const int wave = t >> 6, lane = t & 63;
    if (lane == 0) {
        #pragma unroll
        for (int e = 0; e < NE; ++e) red[wave][e] = pd[e];
    }
    __syncthreads();
    if (t < NE)
        lpart[(size_t)(b * NCHUNK + c) * NE + t] =
            red[0][t] + red[1][t] + red[2][t] + red[3][t];
}

// ---- 2. final logits + softmax + top2 ----
__global__ void krouter2(const float* __restrict__ lpart,
                         float* __restrict__ out_logits,
                         float* __restrict__ selw, int* __restrict__ sele) {
    const int t = threadIdx.x;  // 64
    __shared__ float lg[BS * NE];
    if (t < BS * NE) {
        const int b = t >> 3, e = t & 7;
        float s = 0.f;
        for (int c = 0; c < NCHUNK; ++c) s += lpart[(size_t)(b * NCHUNK + c) * NE + e];
        s *= (1.0f / (float)SEQ);
        lg[b * NE + e] = s;
        out_logits[b * NE + e] = s;
    }
    __syncthreads();
    if (t < BS) {
        float l[NE]; float mx = -1e30f;
        #pragma unroll
        for (int e = 0; e < NE; ++e) { l[e] = lg[t * NE + e]; mx = fmaxf(mx, l[e]); }
        float sum = 0.f;
        #pragma unroll
        for (int e = 0; e < NE; ++e) { l[e] = expf(l[e] - mx); sum += l[e]; }
        const float invs = 1.f / sum;
        float v1 = -1.f, v2 = -1.f; int e1 = -1, e2 = -1;
        #pragma unroll
        for (int e = 0; e < NE; ++e) {
            float pe = l[e] * invs;
            if (pe > v1)      { v2 = v1; e2 = e1; v1 = pe; e1 = e; }
            else if (pe > v2) { v2 = pe; e2 = e; }
        }
        selw[t * 2 + 0] = v1; sele[t * 2 + 0] = e1;
        selw[t * 2 + 1] = v2; sele[t * 2 + 1] = e2;
    }
}

__device__ __forceinline__ int build_slots(const int* __restrict__ sele, int e, int* slot) {
    unsigned mask = 0;
    #pragma unroll
    for (int s = 0; s < NSLOT; ++s) mask |= (sele[s] == e) ? (1u << s) : 0u;
    const int m = __popc(mask);
    unsigned mm = mask;
    #pragma unroll
    for (int ti = 0; ti < MAXM; ++ti) { slot[ti] = __ffs(mm) - 1; mm &= mm - 1; }
    return m;
}

__device__ __forceinline__ void slots_to_lds(const int* __restrict__ sele, int e,
                                             int t, int* sslot) {
    if (t < MAXM) {
        unsigned mask = 0;
        #pragma unroll
        for (int s = 0; s < NSLOT; ++s) mask |= (sele[s] == e) ? (1u << s) : 0u;
        unsigned mm = mask; int sl = -1;
        for (int k = 0; k <= t; ++k) { sl = __ffs(mm) - 1; mm &= mm - 1; }
        sslot[t] = sl;
    }
}

// ======== kswiglu: wave-per-row contiguous loads, 2-row pipeline, fused silu ========
// COMPROW: uses M (template), m, lane, rowbase, act, slot, xs4 from scope.
#define COMPROW(Wa, Wc, RR) {                                                 \
    float u_[M], g_[M];                                                       \
    _Pragma("unroll")                                                         \
    for (int ti_ = 0; ti_ < M; ++ti_) { u_[ti_] = 0.f; g_[ti_] = 0.f; }       \
    _Pragma("unroll")                                                         \
    for (int i_ = 0; i_ < 4; ++i_) {                                          \
        _Pragma("unroll")                                                     \
        for (int ti_ = 0; ti_ < M; ++ti_) {                                   \
            float4 x_ = xs4[ti_ * 256 + i_ * 64];                             \
            u_[ti_] += dot4(Wa[i_], x_);                                      \
            g_[ti_] += dot4(Wc[i_], x_);                                      \
        }                                                                     \
    }                                                                         \
    _Pragma("unroll")                                                         \
    for (int ti_ = 0; ti_ < M; ++ti_) {                                       \
        _Pragma("unroll")                                                     \
        for (int o_ = 32; o_; o_ >>= 1) {                                     \
            u_[ti_] += __shfl_xor(u_[ti_], o_);                               \
            g_[ti_] += __shfl_xor(g_[ti_], o_);                               \
        }                                                                     \
        if (ti_ < m && lane == 0)                                             \
            act[(size_t)slot[ti_] * FF + rowbase + (RR)] =                    \
                (u_[ti_] / (1.f + expf(-u_[ti_]))) * g_[ti_];                 \
    } }

template<int M>
__device__ void swiglu_work(const float4* __restrict__ w1p,   // +rowbase*256+lane
                            const float4* __restrict__ w3p,
                            const float4* __restrict__ xs4,   // +lane
                            float* __restrict__ act,
                            const int* slot, int m, int rowbase, int lane) {
    float4 A0[4], C0[4], A1[4], C1[4];
    #pragma unroll
    for (int i = 0; i < 4; ++i) { A0[i] = w1p[i * 64]; C0[i] = w3p[i * 64]; }
    #pragma unroll 1
    for (int r = 0; r < 8; r += 2) {
        #pragma unroll
        for (int i = 0; i < 4; ++i) {
            A1[i] = w1p[(r + 1) * 256 + i * 64];
            C1[i] = w3p[(r + 1) * 256 + i * 64];
        }
        COMPROW(A0, C0, r)
        if (r + 2 < 8) {
            #pragma unroll
            for (int i = 0; i < 4; ++i) {
                A0[i] = w1p[(r + 2) * 256 + i * 64];
                C0[i] = w3p[(r + 2) * 256 + i * 64];
            }
        }
        COMPROW(A1, C1, r + 1)
    }
}

__global__ __launch_bounds__(256, 4) void kswiglu(const float* __restrict__ h,
                                                  const float* __restrict__ w1,
                                                  const float* __restrict__ w3,
                                                  const int* __restrict__ sele,
                                                  float* __restrict__ act) {
    __shared__ float xs[MAXM * DIM];   // 32 KB
    __shared__ int sslot[MAXM];
    const int tile = blockIdx.x, e = blockIdx.y, t = threadIdx.x;
    int slot[MAXM];
    const int m = build_slots(sele, e, slot);
    if (m == 0) return;
    slots_to_lds(sele, e, t, sslot);
    __syncthreads();
    {   // stage x rows (zero-fill unused): 2048 f4, 8 per thread
        float4* dst = (float4*)xs;
        const float4* h4 = (const float4*)h;
        #pragma unroll
        for (int q = 0; q < 8; ++q) {
            const int idx = t + q * 256;
            const int ti = idx >> 8, j = idx & 255;
            const int s = sslot[ti];
            float4 v = make_float4(0.f, 0.f, 0.f, 0.f);
            if (ti < m) v = h4[((size_t)((s >> 1) * SEQ + (s & 1))) * (DIM/4) + j];
            dst[idx] = v;
        }
    }
    __syncthreads();
    const int wave = t >> 6, lane = t & 63;
    const int rowbase = tile * 32 + wave * 8;
    const float4* w1p = (const float4*)w1 + (size_t)e * FF * 256 + (size_t)rowbase * 256 + lane;
    const float4* w3p = (const float4*)w3 + (size_t)e * FF * 256 + (size_t)rowbase * 256 + lane;
    const float4* xs4 = (const float4*)xs + lane;
    if (m <= 2)      swiglu_work<2>(w1p, w3p, xs4, act, slot, m, rowbase, lane);
    else if (m <= 4) swiglu_work<4>(w1p, w3p, xs4, act, slot, m, rowbase, lane);
    else             swiglu_work<8>(w1p, w3p, xs4, act, slot, m, rowbase, lane);
}

// ======== kdown: 4 rows/wave, act chunked through LDS, selw fused ========
template<int M>
__device__ void down_work(const float4* __restrict__ wp,   // +rowbase*1024+lane
                          const float* __restrict__ act,
                          float* __restrict__ as_,
                          const int* __restrict__ sslot,
                          const float* __restrict__ selw,
                          float* __restrict__ y,
                          const int* slot, int m, int rowbase, int lane, int t) {
    float acc[4][M];
    #pragma unroll
    for (int r = 0; r < 4; ++r)
        #pragma unroll
        for (int ti = 0; ti < M; ++ti) acc[r][ti] = 0.f;
    const float4* as4 = (const float4*)as_ + lane;
    #pragma unroll 1
    for (int kc = 0; kc < 4; ++kc) {
        __syncthreads();
        {   // stage act chunk (zero-fill unused): 2048 f4, 8 per thread
            float4* dst = (float4*)as_;
            const float4* a4 = (const float4*)act;
            #pragma unroll
            for (int q = 0; q < 8; ++q) {
                const int idx = t + q * 256;
                const int ti = idx >> 8, j = idx & 255;
                const int s = sslot[ti];
                float4 v = make_float4(0.f, 0.f, 0.f, 0.f);
                if (ti < m) v = a4[(size_t)s * (FF/4) + kc * 256 + j];
                dst[idx] = v;
            }
        }
        __syncthreads();
        float4 W[4][4];
        #pragma unroll
        for (int r = 0; r < 4; ++r)
            #pragma unroll
            for (int i = 0; i < 4; ++i)
                W[r][i] = wp[r * 1024 + kc * 256 + i * 64];
        #pragma unroll
        for (int i = 0; i < 4; ++i) {
            #pragma unroll
            for (int ti = 0; ti < M; ++ti) {
                float4 x = as4[ti * 256 + i * 64];
                #pragma unroll
                for (int r = 0; r < 4; ++r) acc[r][ti] += dot4(W[r][i], x);
            }
        }
    }
    #pragma unroll
    for (int r = 0; r < 4; ++r)
        #pragma unroll
        for (int ti = 0; ti < M; ++ti) {
            float v = acc[r][ti];
            #pragma unroll
            for (int o = 32; o; o >>= 1) v += __shfl_xor(v, o);
            if (ti < m && lane == 0)
                y[(size_t)slot[ti] * DIM + rowbase + r] = selw[slot[ti]] * v;
        }
}

__global__ __launch_bounds__(256, 4) void kdown(const float* __restrict__ w2,
                                                const float* __restrict__ act,
                                                const int* __restrict__ sele,
                                                const float* __restrict__ selw,
                                                float* __restrict__ y) {
    __shared__ float as_[MAXM * 1024];   // 32 KB
    __shared__ int sslot[MAXM];
    const int tile = blockIdx.x, e = blockIdx.y, t = threadIdx.x;
    int slot[MAXM];
    const int m = build_slots(sele, e, slot);
    if (m == 0) return;
    slots_to_lds(sele, e, t, sslot);
    __syncthreads();
    const int wave = t >> 6, lane = t & 63;
    const int rowbase = tile * 16 + wave * 4;
    const float4* wp = (const float4*)w2 + (size_t)e * DIM * 1024 + (size_t)rowbase * 1024 + lane;
    if (m <= 2)      down_work<2>(wp, act, as_, sslot, selw, y, slot, m, rowbase, lane, t);
    else if (m <= 4) down_work<4>(wp, act, as_, sslot, selw, y, slot, m, rowbase, lane, t);
    else             down_work<8>(wp, act, as_, sslot, selw, y, slot, m, rowbase, lane, t);
}

// ---- combine two selections per batch, broadcast across L ----
__global__ __launch_bounds__(256) void kbcast(const float4* __restrict__ y4,
                                              float4* __restrict__ out4) {
    const int b = blockIdx.y, lg = blockIdx.x, t = threadIdx.x;
    float4 y0 = y4[(size_t)(2 * b) * (DIM/4) + t];
    float4 y1 = y4[(size_t)(2 * b + 1) * (DIM/4) + t];
    float4 c = make_float4(y0.x + y1.x, y0.y + y1.y, y0.z + y1.z, y0.w + y1.w);
    size_t base = ((size_t)b * SEQ + (size_t)lg * 8) * (DIM/4) + t;
    #pragma unroll
    for (int i = 0; i < 8; ++i) out4[base + (size_t)i * (DIM/4)] = c;
}

extern "C" void kernel_launch(void* const* d_in, const int* in_sizes, int n_in,
                              void* d_out, int out_size, void* d_ws, size_t ws_size,
                              hipStream_t stream) {
    const float* h  = (const float*)d_in[0];
    const float* rw = (const float*)d_in[1];
    const float* w1 = (const float*)d_in[2];
    const float* w2 = (const float*)d_in[3];
    const float* w3 = (const float*)d_in[4];
    float* out = (float*)d_out;
    float* ws  = (float*)d_ws;

    float* lpart = ws + WS_LPART;
    float* selw  = ws + WS_SELW;
    int*   sele  = (int*)(ws + WS_SELE);
    float* act   = ws + WS_ACT;
    float* y     = ws + WS_Y;
    float* out_logits = out + (size_t)BS * SEQ * DIM;

    klogit  <<<dim3(NCHUNK, BS), 256, 0, stream>>>((const float4*)h, (const float4*)rw, lpart);
    krouter2<<<1, 64, 0, stream>>>(lpart, out_logits, selw, sele);
    kswiglu <<<dim3(FF / 32, NE), 256, 0, stream>>>(h, w1, w3, sele, act);
    kdown   <<<dim3(DIM / 16, NE), 256, 0, stream>>>(w2, act, sele, selw, y);
    kbcast  <<<dim3(SEQ / 8, BS), 256, 0, stream>>>((const float4*)y, (float4*)out);
}

// Round 12
// 133.401 us; speedup vs baseline: 5.3587x; 1.6031x over previous
//
#include <hip/hip_runtime.h>
#include <math.h>

#define BS 8
#define SEQ 1024
#define DIM 1024
#define FF 4096
#define NE 8
#define NSLOT 16
#define MAXM 8
#define NCHUNK 64

#define KS_UG 4
#define KC_UG (DIM / KS_UG)   // 256 floats = 64 f4 per k-chunk
#define KS_DN 16
#define KC_DN (FF / KS_DN)    // 256 floats = 64 f4 per k-chunk

// ws float offsets
#define WS_LPART 0                               // 4096
#define WS_SELW  (WS_LPART + BS*NCHUNK*NE)       // 16
#define WS_SELE  (WS_SELW + NSLOT)               // 16 (ints)
#define WS_ACT   (WS_SELE + NSLOT)               // [NSLOT][FF] = 65536
#define WS_UPP   (WS_ACT + NSLOT*FF)             // [KS_UG][NSLOT][FF] = 262144
#define WS_GTP   (WS_UPP + KS_UG*NSLOT*FF)       // 262144
#define WS_YP    WS_UPP                          // alias: [KS_DN][NSLOT][DIM] = 262144
#define WS_Y     (WS_GTP + KS_UG*NSLOT*FF)       // 16384

__device__ __forceinline__ float dot4(float4 a, float4 b) {
    return a.x*b.x + a.y*b.y + a.z*b.z + a.w*b.w;
}

// ---- 1. h-chunk sum fused with router dot ----
__global__ __launch_bounds__(256) void klogit(const float4* __restrict__ h4,
                                              const float4* __restrict__ rw4,
                                              float* __restrict__ lpart) {
    const int c = blockIdx.x, b = blockIdx.y, t = threadIdx.x;
    const float4* p = h4 + ((size_t)b * SEQ + (size_t)c * 16) * (DIM/4) + t;
    float4 s = make_float4(0.f, 0.f, 0.f, 0.f);
    #pragma unroll
    for (int i = 0; i < 16; ++i) {
        float4 v = p[(size_t)i * (DIM/4)];
        s.x += v.x; s.y += v.y; s.z += v.z; s.w += v.w;
    }
    float pd[NE];
    #pragma unroll
    for (int e = 0; e < NE; ++e) pd[e] = dot4(s, rw4[(size_t)e * (DIM/4) + t]);
    #pragma unroll
    for (int o = 32; o; o >>= 1) {
        #pragma unroll
        for (int e = 0; e < NE; ++e) pd[e] += __shfl_xor(pd[e], o);
    }
    __shared__ float red[4][NE];
    const int wave = t >> 6, lane = t & 63;
    if (lane == 0) {
        #pragma unroll
        for (int e = 0; e < NE; ++e) red[wave][e] = pd[e];
    }
    __syncthreads();
    if (t < NE)
        lpart[(size_t)(b * NCHUNK + c) * NE + t] =
            red[0][t] + red[1][t] + red[2][t] + red[3][t];
}

// ---- 2. final logits + softmax + top2 ----
__global__ void krouter2(const float* __restrict__ lpart,
                         float* __restrict__ out_logits,
                         float* __restrict__ selw, int* __restrict__ sele) {
    const int t = threadIdx.x;  // 64
    __shared__ float lg[BS * NE];
    if (t < BS * NE) {
        const int b = t >> 3, e = t & 7;
        float s = 0.f;
        for (int c = 0; c < NCHUNK; ++c) s += lpart[(size_t)(b * NCHUNK + c) * NE + e];
        s *= (1.0f / (float)SEQ);
        lg[b * NE + e] = s;
        out_logits[b * NE + e] = s;
    }
    __syncthreads();
    if (t < BS) {
        float l[NE]; float mx = -1e30f;
        #pragma unroll
        for (int e = 0; e < NE; ++e) { l[e] = lg[t * NE + e]; mx = fmaxf(mx, l[e]); }
        float sum = 0.f;
        #pragma unroll
        for (int e = 0; e < NE; ++e) { l[e] = expf(l[e] - mx); sum += l[e]; }
        const float invs = 1.f / sum;
        float v1 = -1.f, v2 = -1.f; int e1 = -1, e2 = -1;
        #pragma unroll
        for (int e = 0; e < NE; ++e) {
            float pe = l[e] * invs;
            if (pe > v1)      { v2 = v1; e2 = e1; v1 = pe; e1 = e; }
            else if (pe > v2) { v2 = pe; e2 = e; }
        }
        selw[t * 2 + 0] = v1; sele[t * 2 + 0] = e1;
        selw[t * 2 + 1] = v2; sele[t * 2 + 1] = e2;
    }
}

__device__ __forceinline__ int build_slots(const int* __restrict__ sele, int e, int* slot) {
    unsigned mask = 0;
    #pragma unroll
    for (int s = 0; s < NSLOT; ++s) mask |= (sele[s] == e) ? (1u << s) : 0u;
    const int m = __popc(mask);
    unsigned mm = mask;
    #pragma unroll
    for (int ti = 0; ti < MAXM; ++ti) { slot[ti] = __ffs(mm) - 1; mm &= mm - 1; }
    return m;
}

__device__ __forceinline__ void slots_to_lds(const int* __restrict__ sele, int e,
                                             int t, int* sslot) {
    if (t < MAXM) {
        unsigned mask = 0;
        #pragma unroll
        for (int s = 0; s < NSLOT; ++s) mask |= (sele[s] == e) ? (1u << s) : 0u;
        unsigned mm = mask; int sl = -1;
        for (int k = 0; k <= t; ++k) { sl = __ffs(mm) - 1; mm &= mm - 1; }
        sslot[t] = sl;
    }
}

// ======== GEMV core: lane-owns-row, single 8xf4 line burst, broadcast x ========
// 8 iterations x (8 back-to-back dwordx4 = 128B x 2 lines, fully consumed
// before the next burst) -> L2 merges same-line requests -> exact fetch.
// One live W buffer (32 VGPR), acc[8], unroll-1 outer: no spill room needed.
__device__ __forceinline__ void gemv_lane8(const float4* __restrict__ wp,
                                           const float4* __restrict__ xs4,
                                           float* acc) {
    #pragma unroll 1
    for (int it = 0; it < 8; ++it) {
        const float4 W0 = wp[it*8+0], W1 = wp[it*8+1], W2 = wp[it*8+2], W3 = wp[it*8+3],
                     W4 = wp[it*8+4], W5 = wp[it*8+5], W6 = wp[it*8+6], W7 = wp[it*8+7];
        const float4* xb = xs4 + it * 8;
        #pragma unroll
        for (int ti = 0; ti < MAXM; ++ti) {
            const float4* xt = xb + ti * 64;
            float a = acc[ti];
            a += dot4(W0, xt[0]); a += dot4(W1, xt[1]);
            a += dot4(W2, xt[2]); a += dot4(W3, xt[3]);
            a += dot4(W4, xt[4]); a += dot4(W5, xt[5]);
            a += dot4(W6, xt[6]); a += dot4(W7, xt[7]);
            acc[ti] = a;
        }
    }
}

// ---- 3. up/gate partials: grid z = (mat, ks), 256 rows/block ----
__global__ __launch_bounds__(256) void kswiglu(const float* __restrict__ h,
                                               const float* __restrict__ w1,
                                               const float* __restrict__ w3,
                                               const int* __restrict__ sele,
                                               float* __restrict__ upp,
                                               float* __restrict__ gtp) {
    __shared__ float xs[MAXM * KC_UG];   // 8 KB
    __shared__ int sslot[MAXM];
    const int tile = blockIdx.x, e = blockIdx.y, t = threadIdx.x;
    const int mat = blockIdx.z & 1, ks = blockIdx.z >> 1;
    int slot[MAXM];
    const int m = build_slots(sele, e, slot);
    if (m == 0) return;
    slots_to_lds(sele, e, t, sslot);
    __syncthreads();
    {   // stage x chunks (zero-fill unused): 512 f4, 2 per thread
        float4* xsw = (float4*)xs;
        const float4* h4 = (const float4*)h;
        #pragma unroll
        for (int q = 0; q < 2; ++q) {
            const int idx = t + q * 256;
            const int ti = idx >> 6, j = idx & 63;
            const int s = sslot[ti];
            float4 v = make_float4(0.f, 0.f, 0.f, 0.f);
            if (ti < m)
                v = h4[((size_t)((s >> 1) * SEQ + (s & 1))) * (DIM/4) + ks * 64 + j];
            xsw[idx] = v;
        }
    }
    __syncthreads();
    const int wave = t >> 6, lane = t & 63;
    const int row = tile * 256 + wave * 64 + lane;       // lane-owned output row
    const float4* wp = (const float4*)(mat ? w3 : w1)
                       + ((size_t)e * FF + row) * (DIM/4) + ks * 64;
    float acc[MAXM];
    #pragma unroll
    for (int ti = 0; ti < MAXM; ++ti) acc[ti] = 0.f;
    gemv_lane8(wp, (const float4*)xs, acc);
    float* outp = (mat ? gtp : upp) + (size_t)ks * NSLOT * FF;
    #pragma unroll
    for (int ti = 0; ti < MAXM; ++ti)
        if (ti < m) outp[(size_t)slot[ti] * FF + row] = acc[ti];
}

// ---- 4. combine up/gate partials + silu -> act ----
__global__ __launch_bounds__(256) void kact(const float* __restrict__ upp,
                                            const float* __restrict__ gtp,
                                            float* __restrict__ act) {
    const int r = blockIdx.x * 256 + threadIdx.x, s = blockIdx.y;
    float u = 0.f, g = 0.f;
    #pragma unroll
    for (int ks = 0; ks < KS_UG; ++ks) {
        u += upp[((size_t)ks * NSLOT + s) * FF + r];
        g += gtp[((size_t)ks * NSLOT + s) * FF + r];
    }
    act[(size_t)s * FF + r] = (u / (1.f + expf(-u))) * g;
}

// ---- 5. down partials: grid z = ks, 256 rows/block ----
__global__ __launch_bounds__(256) void kdown(const float* __restrict__ w2,
                                             const float* __restrict__ act,
                                             const int* __restrict__ sele,
                                             float* __restrict__ yp) {
    __shared__ float xs[MAXM * KC_DN];   // 8 KB
    __shared__ int sslot[MAXM];
    const int tile = blockIdx.x, e = blockIdx.y, ks = blockIdx.z, t = threadIdx.x;
    int slot[MAXM];
    const int m = build_slots(sele, e, slot);
    if (m == 0) return;
    slots_to_lds(sele, e, t, sslot);
    __syncthreads();
    {   // stage act chunks (zero-fill unused)
        float4* xsw = (float4*)xs;
        const float4* a4 = (const float4*)act;
        #pragma unroll
        for (int q = 0; q < 2; ++q) {
            const int idx = t + q * 256;
            const int ti = idx >> 6, j = idx & 63;
            const int s = sslot[ti];
            float4 v = make_float4(0.f, 0.f, 0.f, 0.f);
            if (ti < m) v = a4[(size_t)s * (FF/4) + ks * 64 + j];
            xsw[idx] = v;
        }
    }
    __syncthreads();
    const int wave = t >> 6, lane = t & 63;
    const int row = tile * 256 + wave * 64 + lane;       // output row in DIM
    const float4* wp = (const float4*)w2
                       + ((size_t)e * DIM + row) * (FF/4) + ks * 64;
    float acc[MAXM];
    #pragma unroll
    for (int ti = 0; ti < MAXM; ++ti) acc[ti] = 0.f;
    gemv_lane8(wp, (const float4*)xs, acc);
    float* outp = yp + (size_t)ks * NSLOT * DIM;
    #pragma unroll
    for (int ti = 0; ti < MAXM; ++ti)
        if (ti < m) outp[(size_t)slot[ti] * DIM + row] = acc[ti];
}

// ---- 6. combine down partials x selw -> y ----
__global__ __launch_bounds__(256) void kcomby(const float* __restrict__ yp,
                                              const float* __restrict__ selw,
                                              float* __restrict__ y) {
    const int r = blockIdx.x * 256 + threadIdx.x, s = blockIdx.y;
    float v = 0.f;
    #pragma unroll
    for (int ks = 0; ks < KS_DN; ++ks)
        v += yp[((size_t)ks * NSLOT + s) * DIM + r];
    y[(size_t)s * DIM + r] = selw[s] * v;
}

// ---- 7. combine two selections per batch, broadcast across L ----
__global__ __launch_bounds__(256) void kbcast(const float4* __restrict__ y4,
                                              float4* __restrict__ out4) {
    const int b = blockIdx.y, lg = blockIdx.x, t = threadIdx.x;
    float4 y0 = y4[(size_t)(2 * b) * (DIM/4) + t];
    float4 y1 = y4[(size_t)(2 * b + 1) * (DIM/4) + t];
    float4 c = make_float4(y0.x + y1.x, y0.y + y1.y, y0.z + y1.z, y0.w + y1.w);
    size_t base = ((size_t)b * SEQ + (size_t)lg * 8) * (DIM/4) + t;
    #pragma unroll
    for (int i = 0; i < 8; ++i) out4[base + (size_t)i * (DIM/4)] = c;
}

extern "C" void kernel_launch(void* const* d_in, const int* in_sizes, int n_in,
                              void* d_out, int out_size, void* d_ws, size_t ws_size,
                              hipStream_t stream) {
    const float* h  = (const float*)d_in[0];
    const float* rw = (const float*)d_in[1];
    const float* w1 = (const float*)d_in[2];
    const float* w2 = (const float*)d_in[3];
    const float* w3 = (const float*)d_in[4];
    float* out = (float*)d_out;
    float* ws  = (float*)d_ws;

    float* lpart = ws + WS_LPART;
    float* selw  = ws + WS_SELW;
    int*   sele  = (int*)(ws + WS_SELE);
    float* act   = ws + WS_ACT;
    float* upp   = ws + WS_UPP;
    float* gtp   = ws + WS_GTP;
    float* yp    = ws + WS_YP;
    float* y     = ws + WS_Y;
    float* out_logits = out + (size_t)BS * SEQ * DIM;

    klogit  <<<dim3(NCHUNK, BS), 256, 0, stream>>>((const float4*)h, (const float4*)rw, lpart);
    krouter2<<<1, 64, 0, stream>>>(lpart, out_logits, selw, sele);
    kswiglu <<<dim3(FF / 256, NE, 2 * KS_UG), 256, 0, stream>>>(h, w1, w3, sele, upp, gtp);
    kact    <<<dim3(FF / 256, NSLOT), 256, 0, stream>>>(upp, gtp, act);
    kdown   <<<dim3(DIM / 256, NE, KS_DN), 256, 0, stream>>>(w2, act, sele, yp);
    kcomby  <<<dim3(DIM / 256, NSLOT), 256, 0, stream>>>(yp, selw, y);
    kbcast  <<<dim3(SEQ / 8, BS), 256, 0, stream>>>((const float4*)y, (float4*)out);
}